// Round 1
// baseline (25.156 us; speedup 1.0000x reference)
//
#include <hip/hip_runtime.h>
#include <math.h>

// Problem constants (from reference):
//   B=256, T=512, D_IN=64, HID=64, NB=10, NCLS=2
// Output depends ONLY on x[:, T-1, :]  (lift of other timesteps is dead code).
#define BB   256
#define TT   512
#define DIN  64
#define HIDD 64
#define NBAS 10
#define NCLS 2

__global__ __launch_bounds__(64) void kan_fwd(
    const float* __restrict__ x,
    const float* __restrict__ lift_c, const float* __restrict__ lift_w, const float* __restrict__ lift_coef,
    const float* __restrict__ rnn_c,  const float* __restrict__ rnn_w,  const float* __restrict__ rnn_coef,
    const float* __restrict__ head_c, const float* __restrict__ head_w, const float* __restrict__ head_coef,
    const float* __restrict__ W, const float* __restrict__ bvec,
    float* __restrict__ out)
{
    const int b = blockIdx.x;   // sample
    const int o = threadIdx.x;  // 0..63 : this thread's channel

    __shared__ float phi[DIN][NBAS];

    // cur = this thread's element of the current activation vector.
    float cur = x[((size_t)b * TT + (TT - 1)) * DIN + o];

    // One KAN layer: cur(in channel o) -> phi LDS -> contraction -> cur(out channel o)
    auto layer = [&](const float* __restrict__ cptr,
                     const float* __restrict__ wptr,
                     const float* __restrict__ coef,
                     bool sig) {
        float c[NBAS], iw[NBAS];
        #pragma unroll
        for (int k = 0; k < NBAS; ++k) { c[k] = cptr[k]; iw[k] = 1.0f / wptr[k]; }

        __syncthreads();  // previous layer's phi readers done before overwrite
        #pragma unroll
        for (int k = 0; k < NBAS; ++k)
            phi[o][k] = tanhf((cur - c[k]) * iw[k]);
        __syncthreads();  // phi ready

        float acc = 0.0f;
        #pragma unroll 8
        for (int i = 0; i < DIN; ++i) {
            #pragma unroll
            for (int k = 0; k < NBAS; ++k)
                acc = fmaf(phi[i][k], coef[(i * NBAS + k) * HIDD + o], acc);
        }
        if (sig) acc = 1.0f / (1.0f + expf(-acc));
        cur = acc;
    };

    layer(lift_c, lift_w, lift_coef, /*sig=*/false);  // z   = lift(x_last)
    layer(rnn_c,  rnn_w,  rnn_coef,  /*sig=*/true);   // h   = sigmoid(rnn(z))
    layer(head_c, head_w, head_coef, /*sig=*/true);   // phi = sigmoid(head(h))

    // logits[b][c] = sum_h phi[h] * W[h][c] + bias[c]   (NCLS=2)
    float p0 = cur * W[o * NCLS + 0];
    float p1 = cur * W[o * NCLS + 1];
    #pragma unroll
    for (int off = 32; off > 0; off >>= 1) {
        p0 += __shfl_down(p0, off);
        p1 += __shfl_down(p1, off);
    }
    if (o == 0) {
        out[b * NCLS + 0] = p0 + bvec[0];
        out[b * NCLS + 1] = p1 + bvec[1];
    }
}

extern "C" void kernel_launch(void* const* d_in, const int* in_sizes, int n_in,
                              void* d_out, int out_size, void* d_ws, size_t ws_size,
                              hipStream_t stream) {
    const float* x          = (const float*)d_in[0];
    const float* lift_c     = (const float*)d_in[1];
    const float* lift_w     = (const float*)d_in[2];
    const float* lift_coef  = (const float*)d_in[3];
    const float* rnn_c      = (const float*)d_in[4];
    const float* rnn_w      = (const float*)d_in[5];
    const float* rnn_coef   = (const float*)d_in[6];
    const float* head_c     = (const float*)d_in[7];
    const float* head_w     = (const float*)d_in[8];
    const float* head_coef  = (const float*)d_in[9];
    const float* W          = (const float*)d_in[10];
    const float* bvec       = (const float*)d_in[11];
    float* out              = (float*)d_out;

    kan_fwd<<<dim3(BB), dim3(64), 0, stream>>>(
        x, lift_c, lift_w, lift_coef,
        rnn_c, rnn_w, rnn_coef,
        head_c, head_w, head_coef,
        W, bvec, out);
}

// Round 2
// 12.645 us; speedup vs baseline: 1.9894x; 1.9894x over previous
//
#include <hip/hip_runtime.h>
#include <math.h>

// B=256, T=512, D_IN=64, HID=64, NB=10, NCLS=2
// Output depends ONLY on x[:, T-1, :] (lift of other timesteps is dead code).
#define BB    256
#define TT    512
#define DIN   64
#define HIDD  64
#define NBAS  10
#define NCLS  2

#define NTHR   1024
#define NWAVES (NTHR / 64)            // 16
#define NPHI   (DIN * NBAS)           // 640 (i,k) pairs per layer
#define EPT    (NPHI / NWAVES)        // 40 terms per wave

__global__ __launch_bounds__(NTHR) void kan_fwd(
    const float* __restrict__ x,
    const float* __restrict__ lift_c, const float* __restrict__ lift_w, const float* __restrict__ lift_coef,
    const float* __restrict__ rnn_c,  const float* __restrict__ rnn_w,  const float* __restrict__ rnn_coef,
    const float* __restrict__ head_c, const float* __restrict__ head_w, const float* __restrict__ head_coef,
    const float* __restrict__ W, const float* __restrict__ bvec,
    float* __restrict__ out)
{
    const int b = blockIdx.x;    // sample
    const int t = threadIdx.x;
    const int o = t & 63;        // output channel this thread accumulates
    const int w = t >> 6;        // wave id 0..15 -> i-range slice

    __shared__ float act[DIN];          // current activation vector
    __shared__ float phi[NPHI];         // tanh basis values, flat (i*NB+k)
    __shared__ float part[NWAVES][DIN]; // per-wave partial sums

    if (t < DIN)
        act[t] = x[((size_t)b * TT + (TT - 1)) * DIN + t];

    auto layer = [&](const float* __restrict__ cptr,
                     const float* __restrict__ wptr,
                     const float* __restrict__ coef,
                     bool sig) {
        __syncthreads();                 // act ready / previous phi consumers done
        if (t < NPHI) {
            const int i = t / NBAS;      // magic-mul div by 10
            const int k = t - i * NBAS;
            phi[t] = tanhf((act[i] - cptr[k]) / wptr[k]);
        }
        __syncthreads();                 // phi ready

        // Each wave accumulates EPT consecutive terms for its channel o.
        float a0 = 0.0f, a1 = 0.0f;
        const int e0 = w * EPT;
        const float* cp = coef + (size_t)e0 * HIDD + o;
        #pragma unroll
        for (int e = 0; e < EPT; e += 2) {
            a0 = fmaf(phi[e0 + e],     cp[(e)     * HIDD], a0);  // phi: LDS broadcast
            a1 = fmaf(phi[e0 + e + 1], cp[(e + 1) * HIDD], a1);  // coef: coalesced
        }
        part[w][o] = a0 + a1;
        __syncthreads();                 // partials ready

        if (t < DIN) {
            float s = 0.0f;
            #pragma unroll
            for (int ww = 0; ww < NWAVES; ++ww) s += part[ww][t];
            if (sig) s = 1.0f / (1.0f + expf(-s));
            act[t] = s;
        }
    };

    layer(lift_c, lift_w, lift_coef, /*sig=*/false); // z   = lift(x_last)
    layer(rnn_c,  rnn_w,  rnn_coef,  /*sig=*/true);  // h   = sigmoid(rnn(z))
    layer(head_c, head_w, head_coef, /*sig=*/true);  // phi = sigmoid(head(h))

    // logits[b][c] = sum_h act[h] * W[h][c] + b[c]; wave 0 only (threads 0..63)
    if (t < DIN) {
        const float cur = act[t];        // written by this same thread above
        float p0 = cur * W[t * NCLS + 0];
        float p1 = cur * W[t * NCLS + 1];
        #pragma unroll
        for (int off = 32; off > 0; off >>= 1) {
            p0 += __shfl_down(p0, off);
            p1 += __shfl_down(p1, off);
        }
        if (t == 0) {
            out[b * NCLS + 0] = p0 + bvec[0];
            out[b * NCLS + 1] = p1 + bvec[1];
        }
    }
}

extern "C" void kernel_launch(void* const* d_in, const int* in_sizes, int n_in,
                              void* d_out, int out_size, void* d_ws, size_t ws_size,
                              hipStream_t stream) {
    const float* x          = (const float*)d_in[0];
    const float* lift_c     = (const float*)d_in[1];
    const float* lift_w     = (const float*)d_in[2];
    const float* lift_coef  = (const float*)d_in[3];
    const float* rnn_c      = (const float*)d_in[4];
    const float* rnn_w      = (const float*)d_in[5];
    const float* rnn_coef   = (const float*)d_in[6];
    const float* head_c     = (const float*)d_in[7];
    const float* head_w     = (const float*)d_in[8];
    const float* head_coef  = (const float*)d_in[9];
    const float* W          = (const float*)d_in[10];
    const float* bvec       = (const float*)d_in[11];
    float* out              = (float*)d_out;

    kan_fwd<<<dim3(BB), dim3(NTHR), 0, stream>>>(
        x, lift_c, lift_w, lift_coef,
        rnn_c, rnn_w, rnn_coef,
        head_c, head_w, head_coef,
        W, bvec, out);
}